// Round 1
// baseline (599.721 us; speedup 1.0000x reference)
//
#include <hip/hip_runtime.h>
#include <math.h>

#define L 256
#define DP 128
#define NH 4
#define DH 32
#define NROW 65536   /* L*L */

constexpr int ROWS_A = 32;
constexpr float SCALING = 0.17677669529663687f;  /* 1/sqrt(32) */

// ---------------- Kernel A: LayerNorm + Q/K/V/bias/gate projections ----------------
__global__ __launch_bounds__(256) void ln_proj_kernel(
    const float* __restrict__ pair, const float* __restrict__ gamma, const float* __restrict__ beta,
    const float* __restrict__ Wq, const float* __restrict__ Wk, const float* __restrict__ Wv,
    const float* __restrict__ Wb, const float* __restrict__ Wg, const float* __restrict__ bgv,
    float* __restrict__ qo, float* __restrict__ ko, float* __restrict__ vo,
    float* __restrict__ gateo, float* __restrict__ biasT)
{
    __shared__ __align__(16) float xs[ROWS_A][DP];
    const int t = threadIdx.x;
    const int base = blockIdx.x * ROWS_A;

    // load 32 rows x 128 = 1024 float4
    const float4* p4 = (const float4*)(pair + (size_t)base * DP);
    float4* x4 = (float4*)&xs[0][0];
    #pragma unroll
    for (int it = 0; it < 4; ++it) x4[t + 256 * it] = p4[t + 256 * it];
    __syncthreads();

    const int wave = t >> 6, lane = t & 63;
    {
        const float g0 = gamma[lane], g1 = gamma[lane + 64];
        const float b0 = beta[lane],  b1 = beta[lane + 64];
        #pragma unroll
        for (int rr = 0; rr < ROWS_A / 4; ++rr) {
            int r = wave * (ROWS_A / 4) + rr;
            float e0 = xs[r][lane], e1 = xs[r][lane + 64];
            float s = e0 + e1, ss = e0 * e0 + e1 * e1;
            #pragma unroll
            for (int o = 32; o > 0; o >>= 1) { s += __shfl_xor(s, o); ss += __shfl_xor(ss, o); }
            float mu = s * (1.f / DP);
            float rs = rsqrtf(ss * (1.f / DP) - mu * mu + 1e-5f);
            xs[r][lane]      = (e0 - mu) * rs * g0 + b0;
            xs[r][lane + 64] = (e1 - mu) * rs * g1 + b1;
        }
    }
    __syncthreads();

    const int c = t & 127;
    // pass 1: Wq (threads 0..127) / Wk (threads 128..255)
    {
        const float* W = (t < 128) ? Wq : Wk;
        const float* Wc = W + c;
        float acc[ROWS_A];
        #pragma unroll
        for (int r = 0; r < ROWS_A; ++r) acc[r] = 0.f;
        for (int d4 = 0; d4 < DP / 4; ++d4) {
            float w0 = Wc[(4 * d4 + 0) * DP];
            float w1 = Wc[(4 * d4 + 1) * DP];
            float w2 = Wc[(4 * d4 + 2) * DP];
            float w3 = Wc[(4 * d4 + 3) * DP];
            #pragma unroll
            for (int r = 0; r < ROWS_A; ++r) {
                float4 x = *(const float4*)&xs[r][4 * d4];
                acc[r] = fmaf(x.x, w0, acc[r]);
                acc[r] = fmaf(x.y, w1, acc[r]);
                acc[r] = fmaf(x.z, w2, acc[r]);
                acc[r] = fmaf(x.w, w3, acc[r]);
            }
        }
        float* dst = (t < 128) ? qo : ko;
        const float sc = (t < 128) ? SCALING : 1.f;
        for (int r = 0; r < ROWS_A; ++r) dst[(size_t)(base + r) * DP + c] = acc[r] * sc;
    }
    // pass 2: Wv (threads 0..127) / Wg (threads 128..255)
    {
        const float* W = (t < 128) ? Wv : Wg;
        const float* Wc = W + c;
        float acc[ROWS_A];
        #pragma unroll
        for (int r = 0; r < ROWS_A; ++r) acc[r] = 0.f;
        for (int d4 = 0; d4 < DP / 4; ++d4) {
            float w0 = Wc[(4 * d4 + 0) * DP];
            float w1 = Wc[(4 * d4 + 1) * DP];
            float w2 = Wc[(4 * d4 + 2) * DP];
            float w3 = Wc[(4 * d4 + 3) * DP];
            #pragma unroll
            for (int r = 0; r < ROWS_A; ++r) {
                float4 x = *(const float4*)&xs[r][4 * d4];
                acc[r] = fmaf(x.x, w0, acc[r]);
                acc[r] = fmaf(x.y, w1, acc[r]);
                acc[r] = fmaf(x.z, w2, acc[r]);
                acc[r] = fmaf(x.w, w3, acc[r]);
            }
        }
        if (t < 128) {
            for (int r = 0; r < ROWS_A; ++r) vo[(size_t)(base + r) * DP + c] = acc[r];
        } else {
            float bgc = bgv[c];
            for (int r = 0; r < ROWS_A; ++r)
                gateo[(size_t)(base + r) * DP + c] = 1.f / (1.f + __expf(-(acc[r] + bgc)));
        }
    }
    // pass 3: bias — threads 0..127 cover 32 rows x 4 heads; store transposed [h][row]
    if (t < 128) {
        int r = t >> 2, hh = t & 3;
        float acc = 0.f;
        for (int d = 0; d < DP; ++d) acc = fmaf(xs[r][d], Wb[d * NH + hh], acc);
        biasT[(size_t)hh * NROW + base + r] = acc;
    }
}

// ---------------- Kernel B: attention per (i, h) ----------------
__global__ __launch_bounds__(256) void attn_kernel(
    const float* __restrict__ qi, const float* __restrict__ ki, const float* __restrict__ vi,
    const float* __restrict__ biasT, float* __restrict__ ao)
{
    __shared__ __align__(16) float ks[L][33];
    __shared__ __align__(16) float vs[L][36];
    __shared__ float ps[4][2][264];

    const int h = blockIdx.x & 3, i = blockIdx.x >> 2;
    const int t = threadIdx.x, wave = t >> 6, lane = t & 63;

    const float* kb = ki + (size_t)i * L * DP + h * DH;
    const float* vb = vi + (size_t)i * L * DP + h * DH;
    #pragma unroll
    for (int it = 0; it < 8; ++it) {
        int idx = t + 256 * it;               // 0..2047 float4 units
        int row = idx >> 3, dp = (idx & 7) << 2;
        float4 kf = *(const float4*)(kb + (size_t)row * DP + dp);
        float4 vf = *(const float4*)(vb + (size_t)row * DP + dp);
        ks[row][dp] = kf.x; ks[row][dp + 1] = kf.y; ks[row][dp + 2] = kf.z; ks[row][dp + 3] = kf.w;
        *(float4*)&vs[row][dp] = vf;
    }
    __syncthreads();

    const float* qb = qi + (size_t)i * L * DP + h * DH;
    const float* bb = biasT + (size_t)h * NROW;
    const int d4 = lane & 7, half = lane >> 3;

    for (int jj = 0; jj < 32; ++jj) {
        const int j0 = __builtin_amdgcn_readfirstlane(wave * 64 + jj * 2);
        const float* q0 = qb + (size_t)j0 * DP;
        const float* q1 = q0 + DP;
        float s0[4] = {0, 0, 0, 0}, s1[4] = {0, 0, 0, 0};
        #pragma unroll 8
        for (int d = 0; d < DH; ++d) {
            float qa = q0[d], qc = q1[d];
            #pragma unroll
            for (int kk = 0; kk < 4; ++kk) {
                float kv = ks[kk * 64 + lane][d];
                s0[kk] = fmaf(qa, kv, s0[kk]);
                s1[kk] = fmaf(qc, kv, s1[kk]);
            }
        }
        #pragma unroll
        for (int kk = 0; kk < 4; ++kk) {
            int kidx = kk * 64 + lane;
            s0[kk] += bb[(size_t)j0 * L + kidx];
            s1[kk] += bb[(size_t)(j0 + 1) * L + kidx];
        }
        // softmax over k (both rows)
        float m0 = fmaxf(fmaxf(s0[0], s0[1]), fmaxf(s0[2], s0[3]));
        float m1 = fmaxf(fmaxf(s1[0], s1[1]), fmaxf(s1[2], s1[3]));
        #pragma unroll
        for (int o = 32; o > 0; o >>= 1) {
            m0 = fmaxf(m0, __shfl_xor(m0, o));
            m1 = fmaxf(m1, __shfl_xor(m1, o));
        }
        float t0 = 0.f, t1 = 0.f;
        #pragma unroll
        for (int kk = 0; kk < 4; ++kk) {
            s0[kk] = __expf(s0[kk] - m0); t0 += s0[kk];
            s1[kk] = __expf(s1[kk] - m1); t1 += s1[kk];
        }
        #pragma unroll
        for (int o = 32; o > 0; o >>= 1) { t0 += __shfl_xor(t0, o); t1 += __shfl_xor(t1, o); }
        float r0 = 1.f / t0, r1 = 1.f / t1;
        #pragma unroll
        for (int kk = 0; kk < 4; ++kk) {
            int kidx = kk * 64 + lane;
            int pi = kidx + (kidx >> 5);       // pad: bank-spread
            ps[wave][0][pi] = s0[kk] * r0;
            ps[wave][1][pi] = s1[kk] * r1;
        }
        asm volatile("s_waitcnt lgkmcnt(0)" ::: "memory");
        // PV: lane covers d4 = lane&7 (4 floats), half = lane>>3 covers 32 k's
        float4 a0 = make_float4(0, 0, 0, 0), a1 = make_float4(0, 0, 0, 0);
        #pragma unroll 4
        for (int kk2 = 0; kk2 < 32; ++kk2) {
            int kidx = half * 32 + kk2;
            int pi = kidx + half;
            float p0 = ps[wave][0][pi], p1 = ps[wave][1][pi];
            float4 vv = *(const float4*)&vs[kidx][d4 * 4];
            a0.x = fmaf(p0, vv.x, a0.x); a0.y = fmaf(p0, vv.y, a0.y);
            a0.z = fmaf(p0, vv.z, a0.z); a0.w = fmaf(p0, vv.w, a0.w);
            a1.x = fmaf(p1, vv.x, a1.x); a1.y = fmaf(p1, vv.y, a1.y);
            a1.z = fmaf(p1, vv.z, a1.z); a1.w = fmaf(p1, vv.w, a1.w);
        }
        #pragma unroll
        for (int o = 8; o <= 32; o <<= 1) {
            a0.x += __shfl_xor(a0.x, o); a0.y += __shfl_xor(a0.y, o);
            a0.z += __shfl_xor(a0.z, o); a0.w += __shfl_xor(a0.w, o);
            a1.x += __shfl_xor(a1.x, o); a1.y += __shfl_xor(a1.y, o);
            a1.z += __shfl_xor(a1.z, o); a1.w += __shfl_xor(a1.w, o);
        }
        if (lane < 8) {
            *(float4*)(ao + (size_t)(i * L + j0) * DP + h * DH + d4 * 4) = a0;
            *(float4*)(ao + (size_t)(i * L + j0 + 1) * DP + h * DH + d4 * 4) = a1;
        }
    }
}

// ---------------- Kernel C: out = (gate .* ao) @ Wo + bo ----------------
__global__ __launch_bounds__(256) void out_proj_kernel(
    const float* __restrict__ gate, const float* __restrict__ ao,
    const float* __restrict__ Wo, const float* __restrict__ bo,
    float* __restrict__ out)
{
    __shared__ __align__(16) float xs[32][DP];
    const int t = threadIdx.x;
    const int base = blockIdx.x * 32;
    const float4* g4 = (const float4*)(gate + (size_t)base * DP);
    const float4* a4 = (const float4*)(ao + (size_t)base * DP);
    float4* x4 = (float4*)&xs[0][0];
    #pragma unroll
    for (int it = 0; it < 4; ++it) {
        float4 g = g4[t + 256 * it], a = a4[t + 256 * it];
        x4[t + 256 * it] = make_float4(g.x * a.x, g.y * a.y, g.z * a.z, g.w * a.w);
    }
    __syncthreads();

    const int c = t & 127;
    const int rg = t >> 7;   // 0/1 -> rows rg*16 .. rg*16+15
    const float* Wc = Wo + c;
    float acc[16];
    #pragma unroll
    for (int r = 0; r < 16; ++r) acc[r] = 0.f;
    for (int d4 = 0; d4 < DP / 4; ++d4) {
        float w0 = Wc[(4 * d4 + 0) * DP];
        float w1 = Wc[(4 * d4 + 1) * DP];
        float w2 = Wc[(4 * d4 + 2) * DP];
        float w3 = Wc[(4 * d4 + 3) * DP];
        #pragma unroll
        for (int r = 0; r < 16; ++r) {
            float4 x = *(const float4*)&xs[rg * 16 + r][4 * d4];
            acc[r] = fmaf(x.x, w0, acc[r]);
            acc[r] = fmaf(x.y, w1, acc[r]);
            acc[r] = fmaf(x.z, w2, acc[r]);
            acc[r] = fmaf(x.w, w3, acc[r]);
        }
    }
    float bc = bo[c];
    for (int r = 0; r < 16; ++r)
        out[(size_t)(base + rg * 16 + r) * DP + c] = acc[r] + bc;
}

extern "C" void kernel_launch(void* const* d_in, const int* in_sizes, int n_in,
                              void* d_out, int out_size, void* d_ws, size_t ws_size,
                              hipStream_t stream) {
    const float* pair  = (const float*)d_in[0];
    const float* gamma = (const float*)d_in[1];
    const float* beta  = (const float*)d_in[2];
    const float* Wq    = (const float*)d_in[3];
    const float* Wk    = (const float*)d_in[4];
    const float* Wv    = (const float*)d_in[5];
    const float* Wb    = (const float*)d_in[6];
    const float* Wg    = (const float*)d_in[7];
    const float* bg    = (const float*)d_in[8];
    const float* Wo    = (const float*)d_in[9];
    const float* bo    = (const float*)d_in[10];

    float* ws    = (float*)d_ws;
    float* q     = ws;
    float* k     = q    + (size_t)NROW * DP;
    float* v     = k    + (size_t)NROW * DP;
    float* gate  = v    + (size_t)NROW * DP;
    float* ao    = gate + (size_t)NROW * DP;
    float* biasT = ao   + (size_t)NROW * DP;   // NH * NROW floats

    ln_proj_kernel<<<NROW / ROWS_A, 256, 0, stream>>>(pair, gamma, beta, Wq, Wk, Wv, Wb, Wg, bg,
                                                      q, k, v, gate, biasT);
    attn_kernel<<<L * NH, 256, 0, stream>>>(q, k, v, biasT, ao);
    out_proj_kernel<<<NROW / 32, 256, 0, stream>>>(gate, ao, Wo, bo, (float*)d_out);
}

// Round 3
// 256.742 us; speedup vs baseline: 2.3359x; 2.3359x over previous
//
#include <hip/hip_runtime.h>
#include <math.h>

#define L 256
#define DP 128
#define NH 4
#define DH 32
#define NROW 65536   /* L*L */

typedef unsigned short ushort_t;
typedef __attribute__((ext_vector_type(8))) short short8;
typedef __attribute__((ext_vector_type(4))) float f32x4;

constexpr float SCALING = 0.17677669529663687f;  /* 1/sqrt(32) */

static __device__ __forceinline__ unsigned short f2bf(float f) {
    unsigned u = __builtin_bit_cast(unsigned, f);
    u = u + 0x7fffu + ((u >> 16) & 1u);
    return (unsigned short)(u >> 16);
}
static __device__ __forceinline__ float bf2f(unsigned short h) {
    unsigned u = ((unsigned)h) << 16;
    return __builtin_bit_cast(float, u);
}

// ---------------- prep: transpose/convert weights (runs once per launch, tiny) ----------------
// WtAll[528][128] bf16: rows 0..127 Wq^T*SCALING, 128..255 Wk^T, 256..383 Wv^T,
//                       384..511 Wg^T, 512..515 Wb^T, 516..527 zero
// WohT/WolT[128][128] bf16: Wo^T hi and lo split.
__global__ __launch_bounds__(256) void prep_kernel(
    const float* __restrict__ Wq, const float* __restrict__ Wk, const float* __restrict__ Wv,
    const float* __restrict__ Wb, const float* __restrict__ Wg, const float* __restrict__ Wo,
    ushort_t* __restrict__ WtAll, ushort_t* __restrict__ WohT, ushort_t* __restrict__ WolT)
{
    int rowi = blockIdx.x * 16 + (threadIdx.x >> 4);
    int d0 = (threadIdx.x & 15) * 8;
    #pragma unroll
    for (int dd = 0; dd < 8; ++dd) {
        int d = d0 + dd;
        if (rowi < 512) {
            int n = rowi & 127;
            float val;
            if (rowi < 128)      val = Wq[d * 128 + n] * SCALING;
            else if (rowi < 256) val = Wk[d * 128 + n];
            else if (rowi < 384) val = Wv[d * 128 + n];
            else                 val = Wg[d * 128 + n];
            WtAll[rowi * 128 + d] = f2bf(val);
        } else if (rowi < 516) {
            WtAll[rowi * 128 + d] = f2bf(Wb[d * 4 + (rowi - 512)]);
        } else if (rowi < 528) {
            WtAll[rowi * 128 + d] = 0;
        } else if (rowi < 656) {
            int n = rowi - 528;
            WohT[n * 128 + d] = f2bf(Wo[d * 128 + n]);
        } else {
            int n = rowi - 656;
            float wv = Wo[d * 128 + n];
            unsigned short hb = f2bf(wv);
            WolT[n * 128 + d] = f2bf(wv - bf2f(hb));
        }
    }
}

// ---------------- Kernel A: LayerNorm + MFMA projections ----------------
// 64 rows/block, 4 waves x 16 rows. x staged bf16 in LDS (XOR-swizzled).
__global__ __launch_bounds__(256) void ln_proj_mfma(
    const float* __restrict__ pair, const float* __restrict__ gamma, const float* __restrict__ beta,
    const ushort_t* __restrict__ WtAll, const float* __restrict__ bgv,
    ushort_t* __restrict__ qo, ushort_t* __restrict__ ko, ushort_t* __restrict__ vo,
    float* __restrict__ gateo, float* __restrict__ biasT)
{
    __shared__ __align__(16) unsigned char xs[64 * 256];   // [64 rows][128 bf16], swizzled

    const int t = threadIdx.x;
    const int w = t >> 6, lane = t & 63;
    const int c = lane & 15, g = lane >> 4;
    const int base = blockIdx.x * 64;

    // ---- LN (fp32) -> xs bf16 ----
    {
        const float* pr = pair + ((size_t)base + w * 16) * DP;
        float e0[16], e1[16];
        #pragma unroll
        for (int r = 0; r < 16; ++r) {
            e0[r] = pr[r * DP + lane];
            e1[r] = pr[r * DP + 64 + lane];
        }
        const float g0 = gamma[lane], g1 = gamma[lane + 64];
        const float b0 = beta[lane],  b1 = beta[lane + 64];
        #pragma unroll
        for (int r = 0; r < 16; ++r) {
            float s = e0[r] + e1[r], ss = e0[r] * e0[r] + e1[r] * e1[r];
            #pragma unroll
            for (int o = 32; o > 0; o >>= 1) { s += __shfl_xor(s, o); ss += __shfl_xor(ss, o); }
            float mu = s * (1.f / DP);
            float rq = rsqrtf(ss * (1.f / DP) - mu * mu + 1e-5f);
            int rl = w * 16 + r;
            unsigned swz = (unsigned)((rl & 7) << 4);
            *(ushort_t*)(xs + (((unsigned)(rl * 256 + 2 * lane)) ^ swz)) = f2bf((e0[r] - mu) * rq * g0 + b0);
            *(ushort_t*)(xs + (((unsigned)(rl * 256 + 2 * (lane + 64))) ^ swz)) = f2bf((e1[r] - mu) * rq * g1 + b1);
        }
    }
    __syncthreads();

    // ---- A-fragments for this wave's 16 rows ----
    short8 af[4];
    {
        int rl = w * 16 + c;
        unsigned swz = (unsigned)((rl & 7) << 4);
        #pragma unroll
        for (int kk = 0; kk < 4; ++kk)
            af[kk] = *(const short8*)(xs + (((unsigned)(rl * 256 + kk * 64 + g * 16)) ^ swz));
    }

    // ---- GEMM over 33 n-tiles ----
    const int rowb = base + w * 16 + 4 * g;
    for (int nt = 0; nt < 33; ++nt) {
        f32x4 acc = {0.f, 0.f, 0.f, 0.f};
        const ushort_t* wb = WtAll + (size_t)(nt * 16 + c) * 128 + 8 * g;
        #pragma unroll
        for (int kk = 0; kk < 4; ++kk)
            acc = __builtin_amdgcn_mfma_f32_16x16x32_bf16(af[kk], *(const short8*)(wb + kk * 32), acc, 0, 0, 0);

        int n = nt * 16 + c;
        if (nt < 8) {
            #pragma unroll
            for (int e = 0; e < 4; ++e) qo[(size_t)(rowb + e) * 128 + n] = f2bf(acc[e]);
        } else if (nt < 16) {
            #pragma unroll
            for (int e = 0; e < 4; ++e) ko[(size_t)(rowb + e) * 128 + (n - 128)] = f2bf(acc[e]);
        } else if (nt < 24) {
            #pragma unroll
            for (int e = 0; e < 4; ++e) vo[(size_t)(rowb + e) * 128 + (n - 256)] = f2bf(acc[e]);
        } else if (nt < 32) {
            float bgn = bgv[n - 384];
            #pragma unroll
            for (int e = 0; e < 4; ++e)
                gateo[(size_t)(rowb + e) * 128 + (n - 384)] = 1.f / (1.f + __expf(-(acc[e] + bgn)));
        } else {
            if (c < 4) {
                #pragma unroll
                for (int e = 0; e < 4; ++e) biasT[(size_t)c * NROW + rowb + e] = acc[e];
            }
        }
    }
}

// ---------------- Kernel B: MFMA attention, one block per (i, h) ----------------
__global__ __launch_bounds__(256) void attn_mfma(
    const ushort_t* __restrict__ qbf, const ushort_t* __restrict__ kbf, const ushort_t* __restrict__ vbf,
    const float* __restrict__ biasT, float* __restrict__ ao)
{
    __shared__ __align__(16) unsigned char Kb[256 * 64];     // [256 k][32 bf16], linear
    __shared__ __align__(16) unsigned char Vt[32 * 512];     // [32 d][256 bf16 k'], XOR swizzled
    __shared__ __align__(16) unsigned char Plds[4 * 64 * 80];// per-wave [64 j][40 bf16] (32 used)

    const int h = blockIdx.x & 3, i = blockIdx.x >> 2;
    const int t = threadIdx.x, w = t >> 6, lane = t & 63;
    const int c = lane & 15, g = lane >> 4;

    // ---- stage K (linear row-major) ----
    {
        const ushort_t* kg = kbf + (size_t)(i * 256) * 128 + h * 32;
        #pragma unroll
        for (int it = 0; it < 8; ++it) {
            int idx = it * 256 + t;
            int kr = idx >> 3, dp = idx & 7;
            *(uint2*)(Kb + kr * 64 + dp * 8) = *(const uint2*)(kg + (size_t)kr * 128 + dp * 4);
        }
    }
    // ---- stage V transposed with k-permutation pi(kt*32+ks*16+cc) = kt*32+2cc+ks ----
    {
        const ushort_t* vg = vbf + (size_t)(i * 256) * 128 + h * 32;
        #pragma unroll
        for (int it = 0; it < 4; ++it) {
            int idx = it * 256 + t;
            int kp = idx >> 3, dp = idx & 7;
            int kt = kp >> 4, cc = kp & 15;
            int r0 = kt * 32 + cc;
            uint2 a = *(const uint2*)(vg + (size_t)r0 * 128 + dp * 4);
            uint2 b = *(const uint2*)(vg + (size_t)(r0 + 16) * 128 + dp * 4);
            unsigned av[4] = { a.x & 0xffffu, a.x >> 16, a.y & 0xffffu, a.y >> 16 };
            unsigned bv[4] = { b.x & 0xffffu, b.x >> 16, b.y & 0xffffu, b.y >> 16 };
            int kcolb = kt * 64 + 4 * cc;   // byte offset of k' within row
            #pragma unroll
            for (int dd = 0; dd < 4; ++dd) {
                int d = 4 * dp + dd;
                unsigned pk = (bv[dd] << 16) | av[dd];
                *(unsigned*)(Vt + (((unsigned)(d * 512 + kcolb)) ^ ((unsigned)((d & 7) << 4)))) = pk;
            }
        }
    }
    __syncthreads();

    // ---- Q fragments (4 j-subtiles of this wave's 64 rows) ----
    const int j0 = w * 64;
    short8 qf[4];
    {
        const ushort_t* qg = qbf + (size_t)(i * 256 + j0) * 128 + h * 32;
        #pragma unroll
        for (int jt = 0; jt < 4; ++jt)
            qf[jt] = *(const short8*)(qg + (size_t)(jt * 16 + c) * 128 + 8 * g);
    }

    unsigned char* Pw = Plds + w * 5120;
    const float* biasTh = biasT + (size_t)h * NROW;

    f32x4 O[4][2];
    f32x4 rsum[4];
    #pragma unroll
    for (int jt = 0; jt < 4; ++jt) {
        rsum[jt] = (f32x4){0.f, 0.f, 0.f, 0.f};
        O[jt][0] = (f32x4){0.f, 0.f, 0.f, 0.f};
        O[jt][1] = (f32x4){0.f, 0.f, 0.f, 0.f};
    }

    for (int kt = 0; kt < 8; ++kt) {
        // K B-frags (shared across jt)
        short8 kf[2];
        #pragma unroll
        for (int ks = 0; ks < 2; ++ks)
            kf[ks] = *(const short8*)(Kb + (kt * 32 + ks * 16 + c) * 64 + g * 16);

        // S = Q K^T
        f32x4 s[4][2];
        #pragma unroll
        for (int jt = 0; jt < 4; ++jt) {
            #pragma unroll
            for (int ks = 0; ks < 2; ++ks) {
                f32x4 z = {0.f, 0.f, 0.f, 0.f};
                s[jt][ks] = __builtin_amdgcn_mfma_f32_16x16x32_bf16(qf[jt], kf[ks], z, 0, 0, 0);
            }
        }
        // bias + exp + rowsum + pack P (cols' = 2c + ks)
        #pragma unroll
        for (int jt = 0; jt < 4; ++jt) {
            #pragma unroll
            for (int ks = 0; ks < 2; ++ks) {
                const float* bp = biasTh + (size_t)(j0 + jt * 16 + 4 * g) * 256 + kt * 32 + ks * 16 + c;
                #pragma unroll
                for (int e = 0; e < 4; ++e)
                    s[jt][ks][e] = __expf(s[jt][ks][e] + bp[e * 256]);
            }
            #pragma unroll
            for (int e = 0; e < 4; ++e) {
                rsum[jt][e] += s[jt][0][e] + s[jt][1][e];
                unsigned pk = ((unsigned)f2bf(s[jt][1][e]) << 16) | (unsigned)f2bf(s[jt][0][e]);
                *(unsigned*)(Pw + (jt * 16 + 4 * g + e) * 80 + 4 * c) = pk;
            }
        }
        // PV
        short8 vb0, vb1;
        {
            int d_0 = c, d_1 = 16 + c;
            vb0 = *(const short8*)(Vt + (((unsigned)(d_0 * 512 + kt * 64 + g * 16)) ^ ((unsigned)((d_0 & 7) << 4))));
            vb1 = *(const short8*)(Vt + (((unsigned)(d_1 * 512 + kt * 64 + g * 16)) ^ ((unsigned)((d_1 & 7) << 4))));
        }
        #pragma unroll
        for (int jt = 0; jt < 4; ++jt) {
            short8 pa = *(const short8*)(Pw + (jt * 16 + c) * 80 + g * 16);
            O[jt][0] = __builtin_amdgcn_mfma_f32_16x16x32_bf16(pa, vb0, O[jt][0], 0, 0, 0);
            O[jt][1] = __builtin_amdgcn_mfma_f32_16x16x32_bf16(pa, vb1, O[jt][1], 0, 0, 0);
        }
    }

    // rowsum reduce across the 16 column-lanes (same g group)
    #pragma unroll
    for (int jt = 0; jt < 4; ++jt) {
        #pragma unroll
        for (int e = 0; e < 4; ++e) {
            float v = rsum[jt][e];
            v += __shfl_xor(v, 1); v += __shfl_xor(v, 2);
            v += __shfl_xor(v, 4); v += __shfl_xor(v, 8);
            rsum[jt][e] = 1.f / v;
        }
    }
    // store ao (fp32)
    float* aoB = ao + (size_t)(i * 256 + j0) * 128 + h * 32;
    #pragma unroll
    for (int jt = 0; jt < 4; ++jt) {
        #pragma unroll
        for (int dt = 0; dt < 2; ++dt) {
            #pragma unroll
            for (int e = 0; e < 4; ++e)
                aoB[(size_t)(jt * 16 + 4 * g + e) * 128 + dt * 16 + c] = O[jt][dt][e] * rsum[jt][e];
        }
    }
}

// ---------------- Kernel C: out = (gate .* ao) @ Wo + bo, hi/lo split MFMA ----------------
__global__ __launch_bounds__(256) void out_proj_mfma(
    const float* __restrict__ gate, const float* __restrict__ ao,
    const ushort_t* __restrict__ WohT, const ushort_t* __restrict__ WolT,
    const float* __restrict__ bo, float* __restrict__ out)
{
    __shared__ __align__(16) unsigned char xh[64 * 256];
    __shared__ __align__(16) unsigned char xl[64 * 256];

    const int t = threadIdx.x;
    const int w = t >> 6, lane = t & 63;
    const int c = lane & 15, g = lane >> 4;
    const int base = blockIdx.x * 64;

    // stage x = gate*ao, split hi/lo bf16
    #pragma unroll
    for (int it = 0; it < 8; ++it) {
        int idx = it * 256 + t;
        int row = idx >> 5, c4 = idx & 31;
        float4 gg = *(const float4*)(gate + (size_t)(base + row) * 128 + c4 * 4);
        float4 aa = *(const float4*)(ao + (size_t)(base + row) * 128 + c4 * 4);
        float x0 = gg.x * aa.x, x1 = gg.y * aa.y, x2 = gg.z * aa.z, x3 = gg.w * aa.w;
        unsigned short h0 = f2bf(x0), h1 = f2bf(x1), h2 = f2bf(x2), h3 = f2bf(x3);
        unsigned short l0 = f2bf(x0 - bf2f(h0)), l1 = f2bf(x1 - bf2f(h1));
        unsigned short l2 = f2bf(x2 - bf2f(h2)), l3 = f2bf(x3 - bf2f(h3));
        unsigned swz = (unsigned)((row & 7) << 4);
        uint2 hv = { ((unsigned)h1 << 16) | h0, ((unsigned)h3 << 16) | h2 };
        uint2 lv = { ((unsigned)l1 << 16) | l0, ((unsigned)l3 << 16) | l2 };
        *(uint2*)(xh + (((unsigned)(row * 256 + c4 * 8)) ^ swz)) = hv;
        *(uint2*)(xl + (((unsigned)(row * 256 + c4 * 8)) ^ swz)) = lv;
    }
    __syncthreads();

    short8 ah[4], al[4];
    {
        int rl = w * 16 + c;
        unsigned swz = (unsigned)((rl & 7) << 4);
        #pragma unroll
        for (int kk = 0; kk < 4; ++kk) {
            ah[kk] = *(const short8*)(xh + (((unsigned)(rl * 256 + kk * 64 + g * 16)) ^ swz));
            al[kk] = *(const short8*)(xl + (((unsigned)(rl * 256 + kk * 64 + g * 16)) ^ swz));
        }
    }

    const int rowb = base + w * 16 + 4 * g;
    #pragma unroll 1
    for (int nt = 0; nt < 8; ++nt) {
        f32x4 acc = {0.f, 0.f, 0.f, 0.f};
        const ushort_t* wh = WohT + (size_t)(nt * 16 + c) * 128 + 8 * g;
        const ushort_t* wl = WolT + (size_t)(nt * 16 + c) * 128 + 8 * g;
        #pragma unroll
        for (int kk = 0; kk < 4; ++kk) {
            short8 bh = *(const short8*)(wh + kk * 32);
            short8 bl = *(const short8*)(wl + kk * 32);
            acc = __builtin_amdgcn_mfma_f32_16x16x32_bf16(ah[kk], bh, acc, 0, 0, 0);
            acc = __builtin_amdgcn_mfma_f32_16x16x32_bf16(ah[kk], bl, acc, 0, 0, 0);
            acc = __builtin_amdgcn_mfma_f32_16x16x32_bf16(al[kk], bh, acc, 0, 0, 0);
        }
        int n = nt * 16 + c;
        float bon = bo[n];
        #pragma unroll
        for (int e = 0; e < 4; ++e)
            out[(size_t)(rowb + e) * 128 + n] = acc[e] + bon;
    }
}

extern "C" void kernel_launch(void* const* d_in, const int* in_sizes, int n_in,
                              void* d_out, int out_size, void* d_ws, size_t ws_size,
                              hipStream_t stream) {
    const float* pair  = (const float*)d_in[0];
    const float* gamma = (const float*)d_in[1];
    const float* beta  = (const float*)d_in[2];
    const float* Wq    = (const float*)d_in[3];
    const float* Wk    = (const float*)d_in[4];
    const float* Wv    = (const float*)d_in[5];
    const float* Wb    = (const float*)d_in[6];
    const float* Wg    = (const float*)d_in[7];
    const float* bg    = (const float*)d_in[8];
    const float* Wo    = (const float*)d_in[9];
    const float* bo    = (const float*)d_in[10];

    unsigned char* ws = (unsigned char*)d_ws;
    size_t off = 0;
    ushort_t* q_bf   = (ushort_t*)(ws + off); off += (size_t)NROW * 128 * 2;
    ushort_t* k_bf   = (ushort_t*)(ws + off); off += (size_t)NROW * 128 * 2;
    ushort_t* v_bf   = (ushort_t*)(ws + off); off += (size_t)NROW * 128 * 2;
    float*    gateo  = (float*)(ws + off);    off += (size_t)NROW * 128 * 4;
    float*    ao     = (float*)(ws + off);    off += (size_t)NROW * 128 * 4;
    float*    biasT  = (float*)(ws + off);    off += (size_t)NH * NROW * 4;
    ushort_t* WtAll  = (ushort_t*)(ws + off); off += 528 * 128 * 2;
    ushort_t* WohT   = (ushort_t*)(ws + off); off += 128 * 128 * 2;
    ushort_t* WolT   = (ushort_t*)(ws + off); off += 128 * 128 * 2;

    prep_kernel<<<49, 256, 0, stream>>>(Wq, Wk, Wv, Wb, Wg, Wo, WtAll, WohT, WolT);
    ln_proj_mfma<<<NROW / 64, 256, 0, stream>>>(pair, gamma, beta, WtAll, bg,
                                                q_bf, k_bf, v_bf, gateo, biasT);
    attn_mfma<<<L * NH, 256, 0, stream>>>(q_bf, k_bf, v_bf, biasT, ao);
    out_proj_mfma<<<NROW / 64, 256, 0, stream>>>(gateo, ao, WohT, WolT, bo, (float*)d_out);
}

// Round 5
// 239.483 us; speedup vs baseline: 2.5042x; 1.0721x over previous
//
#include <hip/hip_runtime.h>
#include <math.h>

#define L 256
#define DP 128
#define NH 4
#define DH 32
#define NROW 65536   /* L*L */

typedef unsigned short ushort_t;
typedef __attribute__((ext_vector_type(8))) short short8;
typedef __attribute__((ext_vector_type(4))) float f32x4;

constexpr float SCALING = 0.17677669529663687f;  /* 1/sqrt(32) */

static __device__ __forceinline__ unsigned short f2bf(float f) {
    unsigned u = __builtin_bit_cast(unsigned, f);
    u = u + 0x7fffu + ((u >> 16) & 1u);
    return (unsigned short)(u >> 16);
}
static __device__ __forceinline__ float bf2f(unsigned short h) {
    unsigned u = ((unsigned)h) << 16;
    return __builtin_bit_cast(float, u);
}

// ---------------- prep: transpose/convert weights ----------------
// WtAll[528][128] bf16: rows 0..127 Wq^T*SCALING, 128..255 Wk^T, 256..383 Wv^T,
//                       384..511 Wg^T, 512..515 Wb^T, 516..527 zero
// WohT/WolT[128][128] bf16: Wo^T hi and lo split.
__global__ __launch_bounds__(256) void prep_kernel(
    const float* __restrict__ Wq, const float* __restrict__ Wk, const float* __restrict__ Wv,
    const float* __restrict__ Wb, const float* __restrict__ Wg, const float* __restrict__ Wo,
    ushort_t* __restrict__ WtAll, ushort_t* __restrict__ WohT, ushort_t* __restrict__ WolT)
{
    int rowi = blockIdx.x * 16 + (threadIdx.x >> 4);
    int d0 = (threadIdx.x & 15) * 8;
    #pragma unroll
    for (int dd = 0; dd < 8; ++dd) {
        int d = d0 + dd;
        if (rowi < 512) {
            int n = rowi & 127;
            float val;
            if (rowi < 128)      val = Wq[d * 128 + n] * SCALING;
            else if (rowi < 256) val = Wk[d * 128 + n];
            else if (rowi < 384) val = Wv[d * 128 + n];
            else                 val = Wg[d * 128 + n];
            WtAll[rowi * 128 + d] = f2bf(val);
        } else if (rowi < 516) {
            WtAll[rowi * 128 + d] = f2bf(Wb[d * 4 + (rowi - 512)]);
        } else if (rowi < 528) {
            WtAll[rowi * 128 + d] = 0;
        } else if (rowi < 656) {
            int n = rowi - 528;
            WohT[n * 128 + d] = f2bf(Wo[d * 128 + n]);
        } else {
            int n = rowi - 656;
            float wv = Wo[d * 128 + n];
            unsigned short hb = f2bf(wv);
            WolT[n * 128 + d] = f2bf(wv - bf2f(hb));
        }
    }
}

// ---------------- Kernel A: LayerNorm + MFMA projections ----------------
// 64 rows/block. LN: wave w -> rows w*16..+15. GEMM: wave w -> n-tiles {w+4m},
// each tile: weights loaded ONCE, 4 independent row-group accumulators (ILP).
__global__ __launch_bounds__(256) void ln_proj_mfma(
    const float* __restrict__ pair, const float* __restrict__ gamma, const float* __restrict__ beta,
    const ushort_t* __restrict__ WtAll, const float* __restrict__ bgv,
    ushort_t* __restrict__ qo, ushort_t* __restrict__ ko, ushort_t* __restrict__ vo,
    float* __restrict__ gateo, float* __restrict__ biasT)
{
    __shared__ __align__(16) unsigned char xs[64 * 256];   // [64 rows][128 bf16], swizzled

    const int t = threadIdx.x;
    const int w = t >> 6, lane = t & 63;
    const int c = lane & 15, g = lane >> 4;
    const int base = blockIdx.x * 64;

    // ---- LN (fp32) -> xs bf16 ----
    {
        const float* pr = pair + ((size_t)base + w * 16) * DP;
        float e0[16], e1[16];
        #pragma unroll
        for (int r = 0; r < 16; ++r) {
            e0[r] = pr[r * DP + lane];
            e1[r] = pr[r * DP + 64 + lane];
        }
        const float g0 = gamma[lane], g1 = gamma[lane + 64];
        const float b0 = beta[lane],  b1 = beta[lane + 64];
        #pragma unroll
        for (int r = 0; r < 16; ++r) {
            float s = e0[r] + e1[r], ss = e0[r] * e0[r] + e1[r] * e1[r];
            #pragma unroll
            for (int o = 32; o > 0; o >>= 1) { s += __shfl_xor(s, o); ss += __shfl_xor(ss, o); }
            float mu = s * (1.f / DP);
            float rq = rsqrtf(ss * (1.f / DP) - mu * mu + 1e-5f);
            int rl = w * 16 + r;
            unsigned swz = (unsigned)((rl & 7) << 4);
            *(ushort_t*)(xs + (((unsigned)(rl * 256 + 2 * lane)) ^ swz)) = f2bf((e0[r] - mu) * rq * g0 + b0);
            *(ushort_t*)(xs + (((unsigned)(rl * 256 + 2 * (lane + 64))) ^ swz)) = f2bf((e1[r] - mu) * rq * g1 + b1);
        }
    }
    __syncthreads();

    // ---- GEMM: wave w owns n-tiles {w, w+4, ..., w+28}; wave 3 also tile 32 ----
    const int mtot = (w == 3) ? 9 : 8;
    for (int m = 0; m < mtot; ++m) {
        const int nt = (m < 8) ? (w + 4 * m) : 32;
        const ushort_t* wbp = WtAll + (size_t)(nt * 16 + c) * 128 + 8 * g;
        short8 bw[4];
        #pragma unroll
        for (int kk = 0; kk < 4; ++kk) bw[kk] = *(const short8*)(wbp + kk * 32);

        const int n = nt * 16 + c;
        #pragma unroll
        for (int rg = 0; rg < 4; ++rg) {
            const int rl = rg * 16 + c;
            const unsigned swz = (unsigned)((rl & 7) << 4);
            f32x4 acc = {0.f, 0.f, 0.f, 0.f};
            #pragma unroll
            for (int kk = 0; kk < 4; ++kk) {
                short8 af = *(const short8*)(xs + (((unsigned)(rl * 256 + kk * 64 + g * 16)) ^ swz));
                acc = __builtin_amdgcn_mfma_f32_16x16x32_bf16(af, bw[kk], acc, 0, 0, 0);
            }
            const int rowb = base + rg * 16 + 4 * g;
            if (nt < 8) {
                #pragma unroll
                for (int e = 0; e < 4; ++e) qo[(size_t)(rowb + e) * 128 + n] = f2bf(acc[e]);
            } else if (nt < 16) {
                #pragma unroll
                for (int e = 0; e < 4; ++e) ko[(size_t)(rowb + e) * 128 + (n - 128)] = f2bf(acc[e]);
            } else if (nt < 24) {
                #pragma unroll
                for (int e = 0; e < 4; ++e) vo[(size_t)(rowb + e) * 128 + (n - 256)] = f2bf(acc[e]);
            } else if (nt < 32) {
                float bgn = bgv[n - 384];
                #pragma unroll
                for (int e = 0; e < 4; ++e)
                    gateo[(size_t)(rowb + e) * 128 + (n - 384)] = 1.f / (1.f + __expf(-(acc[e] + bgn)));
            } else {
                if (c < 4) {
                    // bias stored transposed: [h][k*256 + j], row r=(j,k) flattened j*256+k
                    #pragma unroll
                    for (int e = 0; e < 4; ++e) {
                        int r = rowb + e;
                        biasT[(size_t)c * NROW + (r & 255) * 256 + (r >> 8)] = acc[e];
                    }
                }
            }
        }
    }
}

// ---------------- Kernel B: MFMA attention, one block per (i, h) ----------------
__global__ __launch_bounds__(256) void attn_mfma(
    const ushort_t* __restrict__ qbf, const ushort_t* __restrict__ kbf, const ushort_t* __restrict__ vbf,
    const float* __restrict__ biasT, float* __restrict__ ao)
{
    __shared__ __align__(16) unsigned char Kb[256 * 64];     // [256 k][32 bf16], linear
    __shared__ __align__(16) unsigned char Vt[32 * 512];     // [32 d][256 bf16 k'], XOR swizzled
    __shared__ __align__(16) unsigned char Plds[4 * 64 * 80];// per-wave [64 j][40 bf16] (32 used)

    const int h = blockIdx.x & 3, i = blockIdx.x >> 2;
    const int t = threadIdx.x, w = t >> 6, lane = t & 63;
    const int c = lane & 15, g = lane >> 4;

    // ---- stage K (linear row-major) ----
    {
        const ushort_t* kg = kbf + (size_t)(i * 256) * 128 + h * 32;
        #pragma unroll
        for (int it = 0; it < 8; ++it) {
            int idx = it * 256 + t;
            int kr = idx >> 3, dp = idx & 7;
            *(uint2*)(Kb + kr * 64 + dp * 8) = *(const uint2*)(kg + (size_t)kr * 128 + dp * 4);
        }
    }
    // ---- stage V transposed with k-permutation pi(kt*32+ks*16+cc) = kt*32+2cc+ks ----
    {
        const ushort_t* vg = vbf + (size_t)(i * 256) * 128 + h * 32;
        #pragma unroll
        for (int it = 0; it < 4; ++it) {
            int idx = it * 256 + t;
            int kp = idx >> 3, dp = idx & 7;
            int kt = kp >> 4, cc = kp & 15;
            int r0 = kt * 32 + cc;
            uint2 a = *(const uint2*)(vg + (size_t)r0 * 128 + dp * 4);
            uint2 b = *(const uint2*)(vg + (size_t)(r0 + 16) * 128 + dp * 4);
            unsigned av[4] = { a.x & 0xffffu, a.x >> 16, a.y & 0xffffu, a.y >> 16 };
            unsigned bv[4] = { b.x & 0xffffu, b.x >> 16, b.y & 0xffffu, b.y >> 16 };
            int kcolb = kt * 64 + 4 * cc;   // byte offset of k' within row
            #pragma unroll
            for (int dd = 0; dd < 4; ++dd) {
                int d = 4 * dp + dd;
                unsigned pk = (bv[dd] << 16) | av[dd];
                *(unsigned*)(Vt + (((unsigned)(d * 512 + kcolb)) ^ ((unsigned)((d & 7) << 4)))) = pk;
            }
        }
    }
    __syncthreads();

    // ---- Q fragments (4 j-subtiles of this wave's 64 rows) ----
    const int j0 = w * 64;
    short8 qf[4];
    {
        const ushort_t* qg = qbf + (size_t)(i * 256 + j0) * 128 + h * 32;
        #pragma unroll
        for (int jt = 0; jt < 4; ++jt)
            qf[jt] = *(const short8*)(qg + (size_t)(jt * 16 + c) * 128 + 8 * g);
    }

    unsigned char* Pw = Plds + w * 5120;
    const float* biasTh = biasT + (size_t)h * NROW;

    f32x4 O[4][2];
    f32x4 rsum[4];
    #pragma unroll
    for (int jt = 0; jt < 4; ++jt) {
        rsum[jt] = (f32x4){0.f, 0.f, 0.f, 0.f};
        O[jt][0] = (f32x4){0.f, 0.f, 0.f, 0.f};
        O[jt][1] = (f32x4){0.f, 0.f, 0.f, 0.f};
    }

    for (int kt = 0; kt < 8; ++kt) {
        // K B-frags (shared across jt)
        short8 kf[2];
        #pragma unroll
        for (int ks = 0; ks < 2; ++ks)
            kf[ks] = *(const short8*)(Kb + (kt * 32 + ks * 16 + c) * 64 + g * 16);

        // S = Q K^T
        f32x4 s[4][2];
        #pragma unroll
        for (int jt = 0; jt < 4; ++jt) {
            #pragma unroll
            for (int ks = 0; ks < 2; ++ks) {
                f32x4 z = {0.f, 0.f, 0.f, 0.f};
                s[jt][ks] = __builtin_amdgcn_mfma_f32_16x16x32_bf16(qf[jt], kf[ks], z, 0, 0, 0);
            }
        }
        // bias (vec4 over j) + exp + rowsum + pack P (cols' = 2c + ks)
        #pragma unroll
        for (int jt = 0; jt < 4; ++jt) {
            #pragma unroll
            for (int ks = 0; ks < 2; ++ks) {
                const f32x4 bv = *(const f32x4*)(biasTh + (size_t)(kt * 32 + ks * 16 + c) * 256 + (j0 + jt * 16 + 4 * g));
                #pragma unroll
                for (int e = 0; e < 4; ++e)
                    s[jt][ks][e] = __expf(s[jt][ks][e] + bv[e]);
            }
            #pragma unroll
            for (int e = 0; e < 4; ++e) {
                rsum[jt][e] += s[jt][0][e] + s[jt][1][e];
                unsigned pk = ((unsigned)f2bf(s[jt][1][e]) << 16) | (unsigned)f2bf(s[jt][0][e]);
                *(unsigned*)(Pw + (jt * 16 + 4 * g + e) * 80 + 4 * c) = pk;
            }
        }
        // PV
        short8 vb0, vb1;
        {
            int d_0 = c, d_1 = 16 + c;
            vb0 = *(const short8*)(Vt + (((unsigned)(d_0 * 512 + kt * 64 + g * 16)) ^ ((unsigned)((d_0 & 7) << 4))));
            vb1 = *(const short8*)(Vt + (((unsigned)(d_1 * 512 + kt * 64 + g * 16)) ^ ((unsigned)((d_1 & 7) << 4))));
        }
        #pragma unroll
        for (int jt = 0; jt < 4; ++jt) {
            short8 pa = *(const short8*)(Pw + (jt * 16 + c) * 80 + g * 16);
            O[jt][0] = __builtin_amdgcn_mfma_f32_16x16x32_bf16(pa, vb0, O[jt][0], 0, 0, 0);
            O[jt][1] = __builtin_amdgcn_mfma_f32_16x16x32_bf16(pa, vb1, O[jt][1], 0, 0, 0);
        }
    }

    // rowsum reduce across the 16 column-lanes (same g group)
    #pragma unroll
    for (int jt = 0; jt < 4; ++jt) {
        #pragma unroll
        for (int e = 0; e < 4; ++e) {
            float v = rsum[jt][e];
            v += __shfl_xor(v, 1); v += __shfl_xor(v, 2);
            v += __shfl_xor(v, 4); v += __shfl_xor(v, 8);
            rsum[jt][e] = 1.f / v;
        }
    }
    // store ao (fp32)
    float* aoB = ao + (size_t)(i * 256 + j0) * 128 + h * 32;
    #pragma unroll
    for (int jt = 0; jt < 4; ++jt) {
        #pragma unroll
        for (int dt = 0; dt < 2; ++dt) {
            #pragma unroll
            for (int e = 0; e < 4; ++e)
                aoB[(size_t)(jt * 16 + 4 * g + e) * 128 + dt * 16 + c] = O[jt][dt][e] * rsum[jt][e];
        }
    }
}

// ---------------- Kernel C: out = (gate .* ao) @ Wo + bo ----------------
// No LDS: A-frag rows (lane&15) loaded straight from global; gate+hi/lo split in regs.
__global__ __launch_bounds__(256) void out_proj_mfma(
    const float* __restrict__ gate, const float* __restrict__ ao,
    const ushort_t* __restrict__ WohT, const ushort_t* __restrict__ WolT,
    const float* __restrict__ bo, float* __restrict__ out)
{
    const int t = threadIdx.x;
    const int w = t >> 6, lane = t & 63;
    const int c = lane & 15, g = lane >> 4;
    const int base = blockIdx.x * 64;

    // A-fragments: row = base + w*16 + c, k-elems kk*32 + g*8 .. +8
    const size_t arow = (size_t)(base + w * 16 + c) * 128;
    short8 ah[4], al[4];
    #pragma unroll
    for (int kk = 0; kk < 4; ++kk) {
        const float* gp = gate + arow + kk * 32 + g * 8;
        const float* ap = ao + arow + kk * 32 + g * 8;
        f32x4 g0 = *(const f32x4*)gp, g1 = *(const f32x4*)(gp + 4);
        f32x4 a0 = *(const f32x4*)ap, a1 = *(const f32x4*)(ap + 4);
        short8 hv, lv;
        #pragma unroll
        for (int e = 0; e < 4; ++e) {
            float x0 = g0[e] * a0[e];
            float x1 = g1[e] * a1[e];
            unsigned short h0 = f2bf(x0), h1 = f2bf(x1);
            hv[e] = (short)h0; hv[e + 4] = (short)h1;
            lv[e] = (short)f2bf(x0 - bf2f(h0)); lv[e + 4] = (short)f2bf(x1 - bf2f(h1));
        }
        ah[kk] = hv; al[kk] = lv;
    }

    const int rowb = base + w * 16 + 4 * g;
    #pragma unroll 2
    for (int nt = 0; nt < 8; ++nt) {
        f32x4 acc = {0.f, 0.f, 0.f, 0.f};
        const ushort_t* wh = WohT + (size_t)(nt * 16 + c) * 128 + 8 * g;
        const ushort_t* wl = WolT + (size_t)(nt * 16 + c) * 128 + 8 * g;
        #pragma unroll
        for (int kk = 0; kk < 4; ++kk) {
            short8 bh = *(const short8*)(wh + kk * 32);
            short8 bl = *(const short8*)(wl + kk * 32);
            acc = __builtin_amdgcn_mfma_f32_16x16x32_bf16(ah[kk], bh, acc, 0, 0, 0);
            acc = __builtin_amdgcn_mfma_f32_16x16x32_bf16(ah[kk], bl, acc, 0, 0, 0);
            acc = __builtin_amdgcn_mfma_f32_16x16x32_bf16(al[kk], bh, acc, 0, 0, 0);
        }
        int n = nt * 16 + c;
        float bon = bo[n];
        #pragma unroll
        for (int e = 0; e < 4; ++e)
            out[(size_t)(rowb + e) * 128 + n] = acc[e] + bon;
    }
}

extern "C" void kernel_launch(void* const* d_in, const int* in_sizes, int n_in,
                              void* d_out, int out_size, void* d_ws, size_t ws_size,
                              hipStream_t stream) {
    const float* pair  = (const float*)d_in[0];
    const float* gamma = (const float*)d_in[1];
    const float* beta  = (const float*)d_in[2];
    const float* Wq    = (const float*)d_in[3];
    const float* Wk    = (const float*)d_in[4];
    const float* Wv    = (const float*)d_in[5];
    const float* Wb    = (const float*)d_in[6];
    const float* Wg    = (const float*)d_in[7];
    const float* bg    = (const float*)d_in[8];
    const float* Wo    = (const float*)d_in[9];
    const float* bo    = (const float*)d_in[10];

    unsigned char* ws = (unsigned char*)d_ws;
    size_t off = 0;
    ushort_t* q_bf   = (ushort_t*)(ws + off); off += (size_t)NROW * 128 * 2;
    ushort_t* k_bf   = (ushort_t*)(ws + off); off += (size_t)NROW * 128 * 2;
    ushort_t* v_bf   = (ushort_t*)(ws + off); off += (size_t)NROW * 128 * 2;
    float*    gateo  = (float*)(ws + off);    off += (size_t)NROW * 128 * 4;
    float*    ao     = (float*)(ws + off);    off += (size_t)NROW * 128 * 4;
    float*    biasT  = (float*)(ws + off);    off += (size_t)NH * NROW * 4;
    ushort_t* WtAll  = (ushort_t*)(ws + off); off += 528 * 128 * 2;
    ushort_t* WohT   = (ushort_t*)(ws + off); off += 128 * 128 * 2;
    ushort_t* WolT   = (ushort_t*)(ws + off); off += 128 * 128 * 2;

    prep_kernel<<<49, 256, 0, stream>>>(Wq, Wk, Wv, Wb, Wg, Wo, WtAll, WohT, WolT);
    ln_proj_mfma<<<NROW / 64, 256, 0, stream>>>(pair, gamma, beta, WtAll, bg,
                                                q_bf, k_bf, v_bf, gateo, biasT);
    attn_mfma<<<L * NH, 256, 0, stream>>>(q_bf, k_bf, v_bf, biasT, ao);
    out_proj_mfma<<<NROW / 64, 256, 0, stream>>>(gateo, ao, WohT, WolT, bo, (float*)d_out);
}

// Round 7
// 232.359 us; speedup vs baseline: 2.5810x; 1.0307x over previous
//
#include <hip/hip_runtime.h>
#include <math.h>

#define L 256
#define DP 128
#define NH 4
#define DH 32
#define NROW 65536   /* L*L */

typedef unsigned short ushort_t;
typedef __attribute__((ext_vector_type(8))) short short8;
typedef __attribute__((ext_vector_type(4))) float f32x4;
typedef __attribute__((ext_vector_type(4))) unsigned int u32x4;

constexpr float SCALING = 0.17677669529663687f;  /* 1/sqrt(32) */

static __device__ __forceinline__ unsigned short f2bf(float f) {
    unsigned u = __builtin_bit_cast(unsigned, f);
    u = u + 0x7fffu + ((u >> 16) & 1u);
    return (unsigned short)(u >> 16);
}
static __device__ __forceinline__ float bf2f(unsigned short h) {
    unsigned u = ((unsigned)h) << 16;
    return __builtin_bit_cast(float, u);
}
static __device__ __forceinline__ unsigned packbf(float lo, float hi) {
    return ((unsigned)f2bf(hi) << 16) | (unsigned)f2bf(lo);
}

// ---------------- prep: transpose/convert weights ----------------
// WtAll[528][128] bf16: rows 0..127 Wq^T*SCALING, 128..255 Wk^T, 256..383 Wv^T,
//                       384..511 Wg^T, 512..515 Wb^T, 516..527 zero
// WohT/WolT[128][128] bf16: Wo^T hi and lo split.
__global__ __launch_bounds__(256) void prep_kernel(
    const float* __restrict__ Wq, const float* __restrict__ Wk, const float* __restrict__ Wv,
    const float* __restrict__ Wb, const float* __restrict__ Wg, const float* __restrict__ Wo,
    ushort_t* __restrict__ WtAll, ushort_t* __restrict__ WohT, ushort_t* __restrict__ WolT)
{
    int rowi = blockIdx.x * 16 + (threadIdx.x >> 4);
    int d0 = (threadIdx.x & 15) * 8;
    #pragma unroll
    for (int dd = 0; dd < 8; ++dd) {
        int d = d0 + dd;
        if (rowi < 512) {
            int n = rowi & 127;
            float val;
            if (rowi < 128)      val = Wq[d * 128 + n] * SCALING;
            else if (rowi < 256) val = Wk[d * 128 + n];
            else if (rowi < 384) val = Wv[d * 128 + n];
            else                 val = Wg[d * 128 + n];
            WtAll[rowi * 128 + d] = f2bf(val);
        } else if (rowi < 516) {
            WtAll[rowi * 128 + d] = f2bf(Wb[d * 4 + (rowi - 512)]);
        } else if (rowi < 528) {
            WtAll[rowi * 128 + d] = 0;
        } else if (rowi < 656) {
            int n = rowi - 528;
            WohT[n * 128 + d] = f2bf(Wo[d * 128 + n]);
        } else {
            int n = rowi - 656;
            float wv = Wo[d * 128 + n];
            unsigned short hb = f2bf(wv);
            WolT[n * 128 + d] = f2bf(wv - bf2f(hb));
        }
    }
}

// ---------------- Kernel A: LayerNorm + MFMA projections ----------------
__global__ __launch_bounds__(256) void ln_proj_mfma(
    const float* __restrict__ pair, const float* __restrict__ gamma, const float* __restrict__ beta,
    const ushort_t* __restrict__ WtAll, const float* __restrict__ bgv,
    ushort_t* __restrict__ qo, ushort_t* __restrict__ ko, ushort_t* __restrict__ vo,
    float* __restrict__ gateo, float* __restrict__ biasT)
{
    __shared__ __align__(16) unsigned char xs[64 * 256];   // [64 rows][128 bf16], swizzled

    const int t = threadIdx.x;
    const int w = t >> 6, lane = t & 63;
    const int c = lane & 15, g = lane >> 4;
    const int base = blockIdx.x * 64;

    // ---- LN (fp32) -> xs bf16 ----
    {
        const float* pr = pair + ((size_t)base + w * 16) * DP;
        float e0[16], e1[16];
        #pragma unroll
        for (int r = 0; r < 16; ++r) {
            e0[r] = pr[r * DP + lane];
            e1[r] = pr[r * DP + 64 + lane];
        }
        const float g0 = gamma[lane], g1 = gamma[lane + 64];
        const float b0 = beta[lane],  b1 = beta[lane + 64];
        #pragma unroll
        for (int r = 0; r < 16; ++r) {
            float s = e0[r] + e1[r], ss = e0[r] * e0[r] + e1[r] * e1[r];
            #pragma unroll
            for (int o = 32; o > 0; o >>= 1) { s += __shfl_xor(s, o); ss += __shfl_xor(ss, o); }
            float mu = s * (1.f / DP);
            float rq = rsqrtf(ss * (1.f / DP) - mu * mu + 1e-5f);
            int rl = w * 16 + r;
            unsigned swz = (unsigned)((rl & 7) << 4);
            *(ushort_t*)(xs + (((unsigned)(rl * 256 + 2 * lane)) ^ swz)) = f2bf((e0[r] - mu) * rq * g0 + b0);
            *(ushort_t*)(xs + (((unsigned)(rl * 256 + 2 * (lane + 64))) ^ swz)) = f2bf((e1[r] - mu) * rq * g1 + b1);
        }
    }
    __syncthreads();

    // ---- GEMM: wave w owns n-tiles {w, w+4, ..., w+28}; wave 3 also tile 32 ----
    const int mtot = (w == 3) ? 9 : 8;
    for (int m = 0; m < mtot; ++m) {
        const int nt = (m < 8) ? (w + 4 * m) : 32;
        const ushort_t* wbp = WtAll + (size_t)(nt * 16 + c) * 128 + 8 * g;
        short8 bw[4];
        #pragma unroll
        for (int kk = 0; kk < 4; ++kk) bw[kk] = *(const short8*)(wbp + kk * 32);

        const int n = nt * 16 + c;
        #pragma unroll
        for (int rg = 0; rg < 4; ++rg) {
            const int rl = rg * 16 + c;
            const unsigned swz = (unsigned)((rl & 7) << 4);
            f32x4 acc = {0.f, 0.f, 0.f, 0.f};
            #pragma unroll
            for (int kk = 0; kk < 4; ++kk) {
                short8 af = *(const short8*)(xs + (((unsigned)(rl * 256 + kk * 64 + g * 16)) ^ swz));
                acc = __builtin_amdgcn_mfma_f32_16x16x32_bf16(af, bw[kk], acc, 0, 0, 0);
            }
            const int rowb = base + rg * 16 + 4 * g;
            if (nt < 8) {
                #pragma unroll
                for (int e = 0; e < 4; ++e) qo[(size_t)(rowb + e) * 128 + n] = f2bf(acc[e]);
            } else if (nt < 16) {
                #pragma unroll
                for (int e = 0; e < 4; ++e) ko[(size_t)(rowb + e) * 128 + (n - 128)] = f2bf(acc[e]);
            } else if (nt < 24) {
                #pragma unroll
                for (int e = 0; e < 4; ++e) vo[(size_t)(rowb + e) * 128 + (n - 256)] = f2bf(acc[e]);
            } else if (nt < 32) {
                float bgn = bgv[n - 384];
                #pragma unroll
                for (int e = 0; e < 4; ++e)
                    gateo[(size_t)(rowb + e) * 128 + (n - 384)] = 1.f / (1.f + __expf(-(acc[e] + bgn)));
            } else {
                if (c < 4) {
                    // bias stored [h][r], r = flat (j,k) row index of x
                    #pragma unroll
                    for (int e = 0; e < 4; ++e)
                        biasT[(size_t)c * NROW + rowb + e] = acc[e];
                }
            }
        }
    }
}

// ---------------- Kernel B: swapped-operand MFMA attention, block per (i, h) ----------------
// Computes S^T = K Q^T per tile (row=k, col=j): softmax k-reduce is in-register +
// shfl; P^T is directly the PV B-operand (no LDS round-trip). O^T = V^T P^T.
__global__ __launch_bounds__(256) void attn_mfma(
    const ushort_t* __restrict__ qbf, const ushort_t* __restrict__ kbf, const ushort_t* __restrict__ vbf,
    const float* __restrict__ biasT, float* __restrict__ ao)
{
    __shared__ __align__(16) unsigned char Kb[256 * 64];     // [256 k][32 bf16], linear
    __shared__ __align__(16) unsigned char Vt[32 * 512];     // [32 d][256 bf16 k-perm], XOR swizzled

    const int h = blockIdx.x & 3, i = blockIdx.x >> 2;
    const int t = threadIdx.x, w = t >> 6, lane = t & 63;
    const int c = lane & 15, g = lane >> 4;

    // ---- stage K (linear row-major) ----
    {
        const ushort_t* kg = kbf + (size_t)(i * 256) * 128 + h * 32;
        #pragma unroll
        for (int it = 0; it < 8; ++it) {
            int idx = it * 256 + t;
            int kr = idx >> 3, dp = idx & 7;
            *(uint2*)(Kb + kr * 64 + dp * 8) = *(const uint2*)(kg + (size_t)kr * 128 + dp * 4);
        }
    }
    // ---- stage V transposed, k-permuted so PV B-frag = packed S^T registers ----
    // position p = g*8+q holds k = (q<4) ? 4g+q : 16+4g+(q-4); u32 pos cc=p>>1.
    {
        const ushort_t* vg = vbf + (size_t)(i * 256) * 128 + h * 32;
        #pragma unroll
        for (int it = 0; it < 4; ++it) {
            int idx = it * 256 + t;
            int kp = idx >> 3, dp = idx & 7;
            int kt = kp >> 4, cc = kp & 15;
            int a = cc & 3, gg = cc >> 2;
            int k1 = (a < 2) ? (4 * gg + 2 * a) : (12 + 4 * gg + 2 * a);
            int r0 = kt * 32 + k1;
            uint2 va = *(const uint2*)(vg + (size_t)r0 * 128 + dp * 4);        // k1
            uint2 vb = *(const uint2*)(vg + (size_t)(r0 + 1) * 128 + dp * 4);  // k1+1
            unsigned av[4] = { va.x & 0xffffu, va.x >> 16, va.y & 0xffffu, va.y >> 16 };
            unsigned bv[4] = { vb.x & 0xffffu, vb.x >> 16, vb.y & 0xffffu, vb.y >> 16 };
            int kcolb = kt * 64 + 4 * cc;
            #pragma unroll
            for (int dd = 0; dd < 4; ++dd) {
                int d = 4 * dp + dd;
                unsigned pk = (bv[dd] << 16) | av[dd];
                *(unsigned*)(Vt + (((unsigned)(d * 512 + kcolb)) ^ ((unsigned)((d & 7) << 4)))) = pk;
            }
        }
    }
    __syncthreads();

    // ---- Q fragments (B-operand of swapped QK^T): lane holds Q[j=jt*16+c][d=g*8..+7] ----
    const int j0 = w * 64;
    short8 qf[4];
    {
        const ushort_t* qg = qbf + (size_t)(i * 256 + j0) * 128 + h * 32;
        #pragma unroll
        for (int jt = 0; jt < 4; ++jt)
            qf[jt] = *(const short8*)(qg + (size_t)(jt * 16 + c) * 128 + 8 * g);
    }

    const float* biasH = biasT + (size_t)h * NROW;

    f32x4 O[4][2];
    float rsum[4] = {0.f, 0.f, 0.f, 0.f};
    #pragma unroll
    for (int jt = 0; jt < 4; ++jt) {
        O[jt][0] = (f32x4){0.f, 0.f, 0.f, 0.f};
        O[jt][1] = (f32x4){0.f, 0.f, 0.f, 0.f};
    }

    for (int kt = 0; kt < 8; ++kt) {
        // K A-frags: lane holds K[k=kt*32+ks*16+c][d=g*8..+7]
        short8 kf[2];
        #pragma unroll
        for (int ks = 0; ks < 2; ++ks)
            kf[ks] = *(const short8*)(Kb + (kt * 32 + ks * 16 + c) * 64 + g * 16);
        // V^T A-frags: lane holds Vt[d=dt*16+c][k-perm kt*32 + g*8..+7]
        short8 vb0 = *(const short8*)(Vt + (((unsigned)(c * 512 + kt * 64 + g * 16)) ^ ((unsigned)((c & 7) << 4))));
        short8 vb1 = *(const short8*)(Vt + (((unsigned)((16 + c) * 512 + kt * 64 + g * 16)) ^ ((unsigned)(((16 + c) & 7) << 4))));

        #pragma unroll
        for (int jt = 0; jt < 4; ++jt) {
            // S^T tiles: row k_local = ks*16+4g+e, col j = c
            f32x4 s0, s1;
            {
                f32x4 z = {0.f, 0.f, 0.f, 0.f};
                s0 = __builtin_amdgcn_mfma_f32_16x16x32_bf16(kf[0], qf[jt], z, 0, 0, 0);
                s1 = __builtin_amdgcn_mfma_f32_16x16x32_bf16(kf[1], qf[jt], z, 0, 0, 0);
            }
            const int jrow = j0 + jt * 16 + c;
            const f32x4 b0 = *(const f32x4*)(biasH + (size_t)jrow * 256 + kt * 32 + 4 * g);
            const f32x4 b1 = *(const f32x4*)(biasH + (size_t)jrow * 256 + kt * 32 + 16 + 4 * g);
            #pragma unroll
            for (int e = 0; e < 4; ++e) {
                s0[e] = __expf(s0[e] + b0[e]);
                s1[e] = __expf(s1[e] + b1[e]);
            }
            rsum[jt] += (s0[0] + s0[1] + s0[2] + s0[3]) + (s1[0] + s1[1] + s1[2] + s1[3]);
            // P^T B-frag: positions q=0..3 <- s0, q=4..7 <- s1 (pure-C pack, no asm)
            u32x4 pk;
            pk[0] = packbf(s0[0], s0[1]);
            pk[1] = packbf(s0[2], s0[3]);
            pk[2] = packbf(s1[0], s1[1]);
            pk[3] = packbf(s1[2], s1[3]);
            short8 pa = __builtin_bit_cast(short8, pk);
            O[jt][0] = __builtin_amdgcn_mfma_f32_16x16x32_bf16(vb0, pa, O[jt][0], 0, 0, 0);
            O[jt][1] = __builtin_amdgcn_mfma_f32_16x16x32_bf16(vb1, pa, O[jt][1], 0, 0, 0);
        }
    }

    // rowsum: sum over the 4 g-groups (lanes differing in bits 4,5), then invert
    #pragma unroll
    for (int jt = 0; jt < 4; ++jt) {
        float v = rsum[jt];
        v += __shfl_xor(v, 16);
        v += __shfl_xor(v, 32);
        rsum[jt] = 1.f / v;
    }
    // store ao: O^T row d_local=4g+e (contiguous in e -> float4), col j=c
    float* aoB = ao + (size_t)(i * 256 + j0) * 128 + h * 32;
    #pragma unroll
    for (int jt = 0; jt < 4; ++jt) {
        const float inv = rsum[jt];
        #pragma unroll
        for (int dt = 0; dt < 2; ++dt) {
            f32x4 ov;
            #pragma unroll
            for (int e = 0; e < 4; ++e) ov[e] = O[jt][dt][e] * inv;
            *(f32x4*)(aoB + (size_t)(jt * 16 + c) * 128 + dt * 16 + 4 * g) = ov;
        }
    }
}

// ---------------- Kernel C: out = (gate .* ao) @ Wo + bo ----------------
// No LDS: A-frag rows (lane&15) loaded straight from global; gate+hi/lo split in regs.
__global__ __launch_bounds__(256) void out_proj_mfma(
    const float* __restrict__ gate, const float* __restrict__ ao,
    const ushort_t* __restrict__ WohT, const ushort_t* __restrict__ WolT,
    const float* __restrict__ bo, float* __restrict__ out)
{
    const int t = threadIdx.x;
    const int w = t >> 6, lane = t & 63;
    const int c = lane & 15, g = lane >> 4;
    const int base = blockIdx.x * 64;

    // A-fragments: row = base + w*16 + c, k-elems kk*32 + g*8 .. +8
    const size_t arow = (size_t)(base + w * 16 + c) * 128;
    short8 ah[4], al[4];
    #pragma unroll
    for (int kk = 0; kk < 4; ++kk) {
        const float* gp = gate + arow + kk * 32 + g * 8;
        const float* ap = ao + arow + kk * 32 + g * 8;
        f32x4 g0 = *(const f32x4*)gp, g1 = *(const f32x4*)(gp + 4);
        f32x4 a0 = *(const f32x4*)ap, a1 = *(const f32x4*)(ap + 4);
        short8 hv, lv;
        #pragma unroll
        for (int e = 0; e < 4; ++e) {
            float x0 = g0[e] * a0[e];
            float x1 = g1[e] * a1[e];
            unsigned short h0 = f2bf(x0), h1 = f2bf(x1);
            hv[e] = (short)h0; hv[e + 4] = (short)h1;
            lv[e] = (short)f2bf(x0 - bf2f(h0)); lv[e + 4] = (short)f2bf(x1 - bf2f(h1));
        }
        ah[kk] = hv; al[kk] = lv;
    }

    const int rowb = base + w * 16 + 4 * g;
    #pragma unroll 2
    for (int nt = 0; nt < 8; ++nt) {
        f32x4 acc = {0.f, 0.f, 0.f, 0.f};
        const ushort_t* wh = WohT + (size_t)(nt * 16 + c) * 128 + 8 * g;
        const ushort_t* wl = WolT + (size_t)(nt * 16 + c) * 128 + 8 * g;
        #pragma unroll
        for (int kk = 0; kk < 4; ++kk) {
            short8 bh = *(const short8*)(wh + kk * 32);
            short8 bl = *(const short8*)(wl + kk * 32);
            acc = __builtin_amdgcn_mfma_f32_16x16x32_bf16(ah[kk], bh, acc, 0, 0, 0);
            acc = __builtin_amdgcn_mfma_f32_16x16x32_bf16(ah[kk], bl, acc, 0, 0, 0);
            acc = __builtin_amdgcn_mfma_f32_16x16x32_bf16(al[kk], bh, acc, 0, 0, 0);
        }
        int n = nt * 16 + c;
        float bon = bo[n];
        #pragma unroll
        for (int e = 0; e < 4; ++e)
            out[(size_t)(rowb + e) * 128 + n] = acc[e] + bon;
    }
}

extern "C" void kernel_launch(void* const* d_in, const int* in_sizes, int n_in,
                              void* d_out, int out_size, void* d_ws, size_t ws_size,
                              hipStream_t stream) {
    const float* pair  = (const float*)d_in[0];
    const float* gamma = (const float*)d_in[1];
    const float* beta  = (const float*)d_in[2];
    const float* Wq    = (const float*)d_in[3];
    const float* Wk    = (const float*)d_in[4];
    const float* Wv    = (const float*)d_in[5];
    const float* Wb    = (const float*)d_in[6];
    const float* Wg    = (const float*)d_in[7];
    const float* bg    = (const float*)d_in[8];
    const float* Wo    = (const float*)d_in[9];
    const float* bo    = (const float*)d_in[10];

    unsigned char* ws = (unsigned char*)d_ws;
    size_t off = 0;
    ushort_t* q_bf   = (ushort_t*)(ws + off); off += (size_t)NROW * 128 * 2;
    ushort_t* k_bf   = (ushort_t*)(ws + off); off += (size_t)NROW * 128 * 2;
    ushort_t* v_bf   = (ushort_t*)(ws + off); off += (size_t)NROW * 128 * 2;
    float*    gateo  = (float*)(ws + off);    off += (size_t)NROW * 128 * 4;
    float*    ao     = (float*)(ws + off);    off += (size_t)NROW * 128 * 4;
    float*    biasT  = (float*)(ws + off);    off += (size_t)NH * NROW * 4;
    ushort_t* WtAll  = (ushort_t*)(ws + off); off += 528 * 128 * 2;
    ushort_t* WohT   = (ushort_t*)(ws + off); off += 128 * 128 * 2;
    ushort_t* WolT   = (ushort_t*)(ws + off); off += 128 * 128 * 2;

    prep_kernel<<<49, 256, 0, stream>>>(Wq, Wk, Wv, Wb, Wg, Wo, WtAll, WohT, WolT);
    ln_proj_mfma<<<NROW / 64, 256, 0, stream>>>(pair, gamma, beta, WtAll, bg,
                                                q_bf, k_bf, v_bf, gateo, biasT);
    attn_mfma<<<L * NH, 256, 0, stream>>>(q_bf, k_bf, v_bf, biasT, ao);
    out_proj_mfma<<<NROW / 64, 256, 0, stream>>>(gateo, ao, WohT, WolT, bo, (float*)d_out);
}

// Round 8
// 232.023 us; speedup vs baseline: 2.5847x; 1.0014x over previous
//
#include <hip/hip_runtime.h>
#include <math.h>

#define L 256
#define DP 128
#define NH 4
#define DH 32
#define NROW 65536   /* L*L */

typedef unsigned short ushort_t;
typedef __attribute__((ext_vector_type(8))) short short8;
typedef __attribute__((ext_vector_type(4))) float f32x4;
typedef __attribute__((ext_vector_type(4))) unsigned int u32x4;

constexpr float SCALING = 0.17677669529663687f;  /* 1/sqrt(32) */

static __device__ __forceinline__ unsigned short f2bf(float f) {
    unsigned u = __builtin_bit_cast(unsigned, f);
    u = u + 0x7fffu + ((u >> 16) & 1u);
    return (unsigned short)(u >> 16);
}
static __device__ __forceinline__ float bf2f(unsigned short h) {
    unsigned u = ((unsigned)h) << 16;
    return __builtin_bit_cast(float, u);
}
static __device__ __forceinline__ unsigned packbf(float lo, float hi) {
    return ((unsigned)f2bf(hi) << 16) | (unsigned)f2bf(lo);
}

// ---------------- prep: transpose/convert weights ----------------
__global__ __launch_bounds__(256) void prep_kernel(
    const float* __restrict__ Wq, const float* __restrict__ Wk, const float* __restrict__ Wv,
    const float* __restrict__ Wb, const float* __restrict__ Wg, const float* __restrict__ Wo,
    ushort_t* __restrict__ WtAll, ushort_t* __restrict__ WohT, ushort_t* __restrict__ WolT)
{
    int rowi = blockIdx.x * 16 + (threadIdx.x >> 4);
    int d0 = (threadIdx.x & 15) * 8;
    #pragma unroll
    for (int dd = 0; dd < 8; ++dd) {
        int d = d0 + dd;
        if (rowi < 512) {
            int n = rowi & 127;
            float val;
            if (rowi < 128)      val = Wq[d * 128 + n] * SCALING;
            else if (rowi < 256) val = Wk[d * 128 + n];
            else if (rowi < 384) val = Wv[d * 128 + n];
            else                 val = Wg[d * 128 + n];
            WtAll[rowi * 128 + d] = f2bf(val);
        } else if (rowi < 516) {
            WtAll[rowi * 128 + d] = f2bf(Wb[d * 4 + (rowi - 512)]);
        } else if (rowi < 528) {
            WtAll[rowi * 128 + d] = 0;
        } else if (rowi < 656) {
            int n = rowi - 528;
            WohT[n * 128 + d] = f2bf(Wo[d * 128 + n]);
        } else {
            int n = rowi - 656;
            float wv = Wo[d * 128 + n];
            unsigned short hb = f2bf(wv);
            WolT[n * 128 + d] = f2bf(wv - bf2f(hb));
        }
    }
}

// ---------------- Kernel A: LayerNorm + MFMA projections ----------------
// A-fragments hoisted to registers once; n-tile loop is {4 L2 loads -> 16 MFMAs}.
__global__ __launch_bounds__(256) void ln_proj_mfma(
    const float* __restrict__ pair, const float* __restrict__ gamma, const float* __restrict__ beta,
    const ushort_t* __restrict__ WtAll, const float* __restrict__ bgv,
    ushort_t* __restrict__ qo, ushort_t* __restrict__ ko, ushort_t* __restrict__ vo,
    ushort_t* __restrict__ gateo, float* __restrict__ biasT)
{
    __shared__ __align__(16) unsigned char xs[64 * 256];   // [64 rows][128 bf16], swizzled

    const int t = threadIdx.x;
    const int w = t >> 6, lane = t & 63;
    const int c = lane & 15, g = lane >> 4;
    const int base = blockIdx.x * 64;

    // ---- LN (fp32) -> xs bf16 ----
    {
        const float* pr = pair + ((size_t)base + w * 16) * DP;
        float e0[16], e1[16];
        #pragma unroll
        for (int r = 0; r < 16; ++r) {
            e0[r] = pr[r * DP + lane];
            e1[r] = pr[r * DP + 64 + lane];
        }
        const float g0 = gamma[lane], g1 = gamma[lane + 64];
        const float b0 = beta[lane],  b1 = beta[lane + 64];
        #pragma unroll
        for (int r = 0; r < 16; ++r) {
            float s = e0[r] + e1[r], ss = e0[r] * e0[r] + e1[r] * e1[r];
            #pragma unroll
            for (int o = 32; o > 0; o >>= 1) { s += __shfl_xor(s, o); ss += __shfl_xor(ss, o); }
            float mu = s * (1.f / DP);
            float rq = rsqrtf(ss * (1.f / DP) - mu * mu + 1e-5f);
            int rl = w * 16 + r;
            unsigned swz = (unsigned)((rl & 7) << 4);
            *(ushort_t*)(xs + (((unsigned)(rl * 256 + 2 * lane)) ^ swz)) = f2bf((e0[r] - mu) * rq * g0 + b0);
            *(ushort_t*)(xs + (((unsigned)(rl * 256 + 2 * (lane + 64))) ^ swz)) = f2bf((e1[r] - mu) * rq * g1 + b1);
        }
    }
    __syncthreads();

    // ---- hoist all A-fragments for this wave's 4 row-groups ----
    short8 af[4][4];   // [rg][kk]
    #pragma unroll
    for (int rg = 0; rg < 4; ++rg) {
        const int rl = rg * 16 + c;
        const unsigned swz = (unsigned)((rl & 7) << 4);
        #pragma unroll
        for (int kk = 0; kk < 4; ++kk)
            af[rg][kk] = *(const short8*)(xs + (((unsigned)(rl * 256 + kk * 64 + g * 16)) ^ swz));
    }

    // ---- GEMM: wave w owns n-tiles {w, w+4, ..., w+28}; wave 3 also tile 32 ----
    const int mtot = (w == 3) ? 9 : 8;
    for (int m = 0; m < mtot; ++m) {
        const int nt = (m < 8) ? (w + 4 * m) : 32;
        const ushort_t* wbp = WtAll + (size_t)(nt * 16 + c) * 128 + 8 * g;
        short8 bw[4];
        #pragma unroll
        for (int kk = 0; kk < 4; ++kk) bw[kk] = *(const short8*)(wbp + kk * 32);

        const int n = nt * 16 + c;
        #pragma unroll
        for (int rg = 0; rg < 4; ++rg) {
            f32x4 acc = {0.f, 0.f, 0.f, 0.f};
            #pragma unroll
            for (int kk = 0; kk < 4; ++kk)
                acc = __builtin_amdgcn_mfma_f32_16x16x32_bf16(af[rg][kk], bw[kk], acc, 0, 0, 0);

            const int rowb = base + rg * 16 + 4 * g;
            if (nt < 8) {
                #pragma unroll
                for (int e = 0; e < 4; ++e) qo[(size_t)(rowb + e) * 128 + n] = f2bf(acc[e]);
            } else if (nt < 16) {
                #pragma unroll
                for (int e = 0; e < 4; ++e) ko[(size_t)(rowb + e) * 128 + (n - 128)] = f2bf(acc[e]);
            } else if (nt < 24) {
                #pragma unroll
                for (int e = 0; e < 4; ++e) vo[(size_t)(rowb + e) * 128 + (n - 256)] = f2bf(acc[e]);
            } else if (nt < 32) {
                float bgn = bgv[n - 384];
                #pragma unroll
                for (int e = 0; e < 4; ++e)
                    gateo[(size_t)(rowb + e) * 128 + (n - 384)] =
                        f2bf(1.f / (1.f + __expf(-(acc[e] + bgn))));
            } else {
                if (c < 4) {
                    #pragma unroll
                    for (int e = 0; e < 4; ++e)
                        biasT[(size_t)c * NROW + rowb + e] = acc[e];
                }
            }
        }
    }
}

// ---------------- Kernel B: swapped-operand MFMA attention + gate fusion ----------------
// S^T = K Q^T; P^T packed in-register as PV B-operand; O^T = V^T P^T.
// Epilogue: x = gate .* (O * inv), split hi/lo bf16, stored row-major.
__global__ __launch_bounds__(256) void attn_mfma(
    const ushort_t* __restrict__ qbf, const ushort_t* __restrict__ kbf, const ushort_t* __restrict__ vbf,
    const ushort_t* __restrict__ gbf, const float* __restrict__ biasT,
    ushort_t* __restrict__ xh, ushort_t* __restrict__ xl)
{
    __shared__ __align__(16) unsigned char Kb[256 * 64];     // [256 k][32 bf16], linear
    __shared__ __align__(16) unsigned char Vt[32 * 512];     // [32 d][256 bf16 k-perm], XOR swizzled

    const int h = blockIdx.x & 3, i = blockIdx.x >> 2;
    const int t = threadIdx.x, w = t >> 6, lane = t & 63;
    const int c = lane & 15, g = lane >> 4;

    // ---- stage K (linear row-major) ----
    {
        const ushort_t* kg = kbf + (size_t)(i * 256) * 128 + h * 32;
        #pragma unroll
        for (int it = 0; it < 8; ++it) {
            int idx = it * 256 + t;
            int kr = idx >> 3, dp = idx & 7;
            *(uint2*)(Kb + kr * 64 + dp * 8) = *(const uint2*)(kg + (size_t)kr * 128 + dp * 4);
        }
    }
    // ---- stage V transposed, k-permuted: pos p=g*8+q holds k=(q<4)?4g+q:16+4g+(q-4) ----
    {
        const ushort_t* vg = vbf + (size_t)(i * 256) * 128 + h * 32;
        #pragma unroll
        for (int it = 0; it < 4; ++it) {
            int idx = it * 256 + t;
            int kp = idx >> 3, dp = idx & 7;
            int kt = kp >> 4, cc = kp & 15;
            int a = cc & 3, gg = cc >> 2;
            int k1 = (a < 2) ? (4 * gg + 2 * a) : (12 + 4 * gg + 2 * a);
            int r0 = kt * 32 + k1;
            uint2 va = *(const uint2*)(vg + (size_t)r0 * 128 + dp * 4);
            uint2 vb = *(const uint2*)(vg + (size_t)(r0 + 1) * 128 + dp * 4);
            unsigned av[4] = { va.x & 0xffffu, va.x >> 16, va.y & 0xffffu, va.y >> 16 };
            unsigned bv[4] = { vb.x & 0xffffu, vb.x >> 16, vb.y & 0xffffu, vb.y >> 16 };
            int kcolb = kt * 64 + 4 * cc;
            #pragma unroll
            for (int dd = 0; dd < 4; ++dd) {
                int d = 4 * dp + dd;
                unsigned pk = (bv[dd] << 16) | av[dd];
                *(unsigned*)(Vt + (((unsigned)(d * 512 + kcolb)) ^ ((unsigned)((d & 7) << 4)))) = pk;
            }
        }
    }
    __syncthreads();

    // ---- Q fragments: lane holds Q[j=jt*16+c][d=g*8..+7] ----
    const int j0 = w * 64;
    short8 qf[4];
    {
        const ushort_t* qg = qbf + (size_t)(i * 256 + j0) * 128 + h * 32;
        #pragma unroll
        for (int jt = 0; jt < 4; ++jt)
            qf[jt] = *(const short8*)(qg + (size_t)(jt * 16 + c) * 128 + 8 * g);
    }

    const float* biasH = biasT + (size_t)h * NROW;

    f32x4 O[4][2];
    float rsum[4] = {0.f, 0.f, 0.f, 0.f};
    #pragma unroll
    for (int jt = 0; jt < 4; ++jt) {
        O[jt][0] = (f32x4){0.f, 0.f, 0.f, 0.f};
        O[jt][1] = (f32x4){0.f, 0.f, 0.f, 0.f};
    }

    for (int kt = 0; kt < 8; ++kt) {
        short8 kf[2];
        #pragma unroll
        for (int ks = 0; ks < 2; ++ks)
            kf[ks] = *(const short8*)(Kb + (kt * 32 + ks * 16 + c) * 64 + g * 16);
        short8 vb0 = *(const short8*)(Vt + (((unsigned)(c * 512 + kt * 64 + g * 16)) ^ ((unsigned)((c & 7) << 4))));
        short8 vb1 = *(const short8*)(Vt + (((unsigned)((16 + c) * 512 + kt * 64 + g * 16)) ^ ((unsigned)(((16 + c) & 7) << 4))));

        #pragma unroll
        for (int jt = 0; jt < 4; ++jt) {
            f32x4 s0, s1;
            {
                f32x4 z = {0.f, 0.f, 0.f, 0.f};
                s0 = __builtin_amdgcn_mfma_f32_16x16x32_bf16(kf[0], qf[jt], z, 0, 0, 0);
                s1 = __builtin_amdgcn_mfma_f32_16x16x32_bf16(kf[1], qf[jt], z, 0, 0, 0);
            }
            const int jrow = j0 + jt * 16 + c;
            const f32x4 b0 = *(const f32x4*)(biasH + (size_t)jrow * 256 + kt * 32 + 4 * g);
            const f32x4 b1 = *(const f32x4*)(biasH + (size_t)jrow * 256 + kt * 32 + 16 + 4 * g);
            #pragma unroll
            for (int e = 0; e < 4; ++e) {
                s0[e] = __expf(s0[e] + b0[e]);
                s1[e] = __expf(s1[e] + b1[e]);
            }
            rsum[jt] += (s0[0] + s0[1] + s0[2] + s0[3]) + (s1[0] + s1[1] + s1[2] + s1[3]);
            u32x4 pk;
            pk[0] = packbf(s0[0], s0[1]);
            pk[1] = packbf(s0[2], s0[3]);
            pk[2] = packbf(s1[0], s1[1]);
            pk[3] = packbf(s1[2], s1[3]);
            short8 pa = __builtin_bit_cast(short8, pk);
            O[jt][0] = __builtin_amdgcn_mfma_f32_16x16x32_bf16(vb0, pa, O[jt][0], 0, 0, 0);
            O[jt][1] = __builtin_amdgcn_mfma_f32_16x16x32_bf16(vb1, pa, O[jt][1], 0, 0, 0);
        }
    }

    // rowsum over g-groups
    #pragma unroll
    for (int jt = 0; jt < 4; ++jt) {
        float v = rsum[jt];
        v += __shfl_xor(v, 16);
        v += __shfl_xor(v, 32);
        rsum[jt] = 1.f / v;
    }
    // epilogue: x = gate .* (O*inv), hi/lo bf16, store
    const ushort_t* gB = gbf + (size_t)(i * 256 + j0) * 128 + h * 32;
    ushort_t* xhB = xh + (size_t)(i * 256 + j0) * 128 + h * 32;
    ushort_t* xlB = xl + (size_t)(i * 256 + j0) * 128 + h * 32;
    #pragma unroll
    for (int jt = 0; jt < 4; ++jt) {
        const float inv = rsum[jt];
        #pragma unroll
        for (int dt = 0; dt < 2; ++dt) {
            const int off = (jt * 16 + c) * 128 + dt * 16 + 4 * g;
            uint2 gv = *(const uint2*)(gB + off);
            unsigned gs[4] = { gv.x & 0xffffu, gv.x >> 16, gv.y & 0xffffu, gv.y >> 16 };
            float xq[4];
            unsigned short hq[4];
            #pragma unroll
            for (int e = 0; e < 4; ++e) {
                xq[e] = bf2f((unsigned short)gs[e]) * O[jt][dt][e] * inv;
                hq[e] = f2bf(xq[e]);
            }
            uint2 hv, lv;
            hv.x = ((unsigned)hq[1] << 16) | hq[0];
            hv.y = ((unsigned)hq[3] << 16) | hq[2];
            lv.x = packbf(xq[0] - bf2f(hq[0]), xq[1] - bf2f(hq[1]));
            lv.y = packbf(xq[2] - bf2f(hq[2]), xq[3] - bf2f(hq[3]));
            *(uint2*)(xhB + off) = hv;
            *(uint2*)(xlB + off) = lv;
        }
    }
}

// ---------------- Kernel C: out = x @ Wo + bo, x = xh+xl bf16 pair ----------------
__global__ __launch_bounds__(256) void out_proj_mfma(
    const ushort_t* __restrict__ xh, const ushort_t* __restrict__ xl,
    const ushort_t* __restrict__ WohT, const ushort_t* __restrict__ WolT,
    const float* __restrict__ bo, float* __restrict__ out)
{
    const int t = threadIdx.x;
    const int w = t >> 6, lane = t & 63;
    const int c = lane & 15, g = lane >> 4;
    const int base = blockIdx.x * 64;

    const size_t arow = (size_t)(base + w * 16 + c) * 128;
    short8 ah[4], al[4];
    #pragma unroll
    for (int kk = 0; kk < 4; ++kk) {
        ah[kk] = *(const short8*)(xh + arow + kk * 32 + g * 8);
        al[kk] = *(const short8*)(xl + arow + kk * 32 + g * 8);
    }

    const int rowb = base + w * 16 + 4 * g;
    #pragma unroll 2
    for (int nt = 0; nt < 8; ++nt) {
        f32x4 acc = {0.f, 0.f, 0.f, 0.f};
        const ushort_t* wh = WohT + (size_t)(nt * 16 + c) * 128 + 8 * g;
        const ushort_t* wl = WolT + (size_t)(nt * 16 + c) * 128 + 8 * g;
        #pragma unroll
        for (int kk = 0; kk < 4; ++kk) {
            short8 bh = *(const short8*)(wh + kk * 32);
            short8 bl = *(const short8*)(wl + kk * 32);
            acc = __builtin_amdgcn_mfma_f32_16x16x32_bf16(ah[kk], bh, acc, 0, 0, 0);
            acc = __builtin_amdgcn_mfma_f32_16x16x32_bf16(ah[kk], bl, acc, 0, 0, 0);
            acc = __builtin_amdgcn_mfma_f32_16x16x32_bf16(al[kk], bh, acc, 0, 0, 0);
        }
        int n = nt * 16 + c;
        float bon = bo[n];
        #pragma unroll
        for (int e = 0; e < 4; ++e)
            out[(size_t)(rowb + e) * 128 + n] = acc[e] + bon;
    }
}

extern "C" void kernel_launch(void* const* d_in, const int* in_sizes, int n_in,
                              void* d_out, int out_size, void* d_ws, size_t ws_size,
                              hipStream_t stream) {
    const float* pair  = (const float*)d_in[0];
    const float* gamma = (const float*)d_in[1];
    const float* beta  = (const float*)d_in[2];
    const float* Wq    = (const float*)d_in[3];
    const float* Wk    = (const float*)d_in[4];
    const float* Wv    = (const float*)d_in[5];
    const float* Wb    = (const float*)d_in[6];
    const float* Wg    = (const float*)d_in[7];
    const float* bg    = (const float*)d_in[8];
    const float* Wo    = (const float*)d_in[9];
    const float* bo    = (const float*)d_in[10];

    unsigned char* ws = (unsigned char*)d_ws;
    size_t off = 0;
    ushort_t* q_bf   = (ushort_t*)(ws + off); off += (size_t)NROW * 128 * 2;
    ushort_t* k_bf   = (ushort_t*)(ws + off); off += (size_t)NROW * 128 * 2;
    ushort_t* v_bf   = (ushort_t*)(ws + off); off += (size_t)NROW * 128 * 2;
    ushort_t* g_bf   = (ushort_t*)(ws + off); off += (size_t)NROW * 128 * 2;
    ushort_t* xh_bf  = (ushort_t*)(ws + off); off += (size_t)NROW * 128 * 2;
    ushort_t* xl_bf  = (ushort_t*)(ws + off); off += (size_t)NROW * 128 * 2;
    float*    biasT  = (float*)(ws + off);    off += (size_t)NH * NROW * 4;
    ushort_t* WtAll  = (ushort_t*)(ws + off); off += 528 * 128 * 2;
    ushort_t* WohT   = (ushort_t*)(ws + off); off += 128 * 128 * 2;
    ushort_t* WolT   = (ushort_t*)(ws + off); off += 128 * 128 * 2;

    prep_kernel<<<49, 256, 0, stream>>>(Wq, Wk, Wv, Wb, Wg, Wo, WtAll, WohT, WolT);
    ln_proj_mfma<<<NROW / 64, 256, 0, stream>>>(pair, gamma, beta, WtAll, bg,
                                                q_bf, k_bf, v_bf, g_bf, biasT);
    attn_mfma<<<L * NH, 256, 0, stream>>>(q_bf, k_bf, v_bf, g_bf, biasT, xh_bf, xl_bf);
    out_proj_mfma<<<NROW / 64, 256, 0, stream>>>(xh_bf, xl_bf, WohT, WolT, bo, (float*)d_out);
}